// Round 3
// baseline (1210.904 us; speedup 1.0000x reference)
//
#include <hip/hip_runtime.h>

#define H 128
#define RREL 8
#define NJ 9        // 8 relations + root
#define MT 32       // dsts per layer-block
#define SF 1028     // fp32 agg row stride (floats): 16B-aligned, +4-dword bank spread per row
#define SB 1032     // bf16 agg row stride (shorts)

typedef short bf16x8 __attribute__((ext_vector_type(8)));
typedef float f32x4 __attribute__((ext_vector_type(4)));
typedef unsigned short u16x8 __attribute__((ext_vector_type(8)));
typedef unsigned short u16x4 __attribute__((ext_vector_type(4)));

static __device__ __forceinline__ unsigned short f2bf(float f) {
    unsigned int u = __float_as_uint(f);
    unsigned int r = (u + 0x7fffu + ((u >> 16) & 1u)) >> 16;
    return (unsigned short)r;
}
static __device__ __forceinline__ float bf2f(unsigned short u) {
    return __uint_as_float(((unsigned int)u) << 16);
}

__global__ void zero_kernel(int* p, long n) {
    long i = (long)blockIdx.x * blockDim.x + threadIdx.x;
    long stride = (long)gridDim.x * blockDim.x;
    for (; i < n; i += stride) p[i] = 0;
}

__global__ void count_kernel(const int* __restrict__ ei, const int* __restrict__ et,
                             int* __restrict__ cnt, int E) {
    int e = blockIdx.x * 256 + threadIdx.x;
    if (e >= E) return;
    int d = ei[E + e];
    int r = et[e];
    atomicAdd(&cnt[(size_t)d * RREL + r], 1);
}

__global__ void scan_block_kernel(const int* __restrict__ cnt, int* __restrict__ rploc,
                                  int* __restrict__ bsum, int N) {
    __shared__ int s[256];
    int t = threadIdx.x;
    int d = blockIdx.x * 256 + t;
    int v = 0;
    if (d < N) {
#pragma unroll
        for (int r = 0; r < RREL; ++r) v += cnt[(size_t)d * RREL + r];
    }
    s[t] = v;
    __syncthreads();
#pragma unroll
    for (int off = 1; off < 256; off <<= 1) {
        int u = 0;
        if (t >= off) u = s[t - off];
        __syncthreads();
        s[t] += u;
        __syncthreads();
    }
    if (d < N) rploc[d] = s[t] - v;
    if (t == 255) bsum[blockIdx.x] = s[255];
}

// finalize with inlined top-level scan of bsum (nb <= 256).
// rowptr[d] = dst-bin start; rowptr2[d*8+r] = (dst,rel)-subbin start; inv = 1/max(cnt,1)
__global__ void finalize_kernel(const int* __restrict__ cnt, const int* __restrict__ rploc,
                                const int* __restrict__ bsum, int* __restrict__ rowptr,
                                int* __restrict__ rowptr2, float* __restrict__ inv,
                                int N, int nb) {
    __shared__ int s[256];
    int t = threadIdx.x;
    int v = (t < nb) ? bsum[t] : 0;
    s[t] = v;
    __syncthreads();
#pragma unroll
    for (int off = 1; off < 256; off <<= 1) {
        int u = 0;
        if (t >= off) u = s[t - off];
        __syncthreads();
        s[t] += u;
        __syncthreads();
    }
    int boffB = (blockIdx.x == 0) ? 0 : s[blockIdx.x - 1];
    int d = blockIdx.x * 256 + t;
    if (d >= N) return;
    int rp = rploc[d] + boffB;
    rowptr[d] = rp;
    int run = rp;
#pragma unroll
    for (int r = 0; r < RREL; ++r) {
        int c = cnt[(size_t)d * RREL + r];
        rowptr2[(size_t)d * RREL + r] = run;
        inv[(size_t)d * RREL + r] = 1.0f / (float)max(c, 1);
        run += c;
    }
    if (d == N - 1) rowptr[N] = run;
}

// packed[pos] = src | (rel<<20) | (dloc<<23), binned by (dst, rel)
__global__ void fill_kernel(const int* __restrict__ ei, const int* __restrict__ et,
                            int* __restrict__ cursor, const int* __restrict__ rowptr2,
                            int* __restrict__ packed, int E) {
    int e = blockIdx.x * 256 + threadIdx.x;
    if (e >= E) return;
    int d = ei[E + e];
    int r = et[e];
    size_t bin = (size_t)d * RREL + r;
    int pos = rowptr2[bin] + atomicAdd(&cursor[bin], 1);
    packed[pos] = ei[e] | (r << 20) | ((d & (MT - 1)) << 23);
}

// Fused weight prep + x->bf16 conversion (grid-stride over both ranges).
// WTa[j][f][k] = W[j][k][f] (j<8) or root[k][f] (j==8); bias natural order.
__global__ void wcat_tobf_kernel(const float* __restrict__ W1, const float* __restrict__ r1,
                                 const float* __restrict__ W2, const float* __restrict__ r2,
                                 const float* __restrict__ b1, const float* __restrict__ b2,
                                 unsigned short* __restrict__ WTa1, unsigned short* __restrict__ WTa2,
                                 float* __restrict__ biasP,
                                 const float* __restrict__ x, unsigned short* __restrict__ xb,
                                 long nx) {
    const long per = (long)NJ * H * H;
    const long total = per + 2 * H + nx;
    for (long id = (long)blockIdx.x * 256 + threadIdx.x; id < total; id += (long)gridDim.x * 256) {
        if (id < per) {
            int j = (int)(id / (H * H));
            int fk = (int)(id - (long)j * (H * H));
            int f = fk >> 7, k = fk & 127;
            float v1 = (j < RREL) ? W1[((size_t)j * H + k) * H + f] : r1[(size_t)k * H + f];
            WTa1[id] = f2bf(v1);
            float v2 = (j < RREL) ? W2[((size_t)j * H + k) * H + f] : r2[(size_t)k * H + f];
            WTa2[id] = f2bf(v2);
        } else if (id < per + 2 * H) {
            int c = (int)(id - per);
            biasP[c] = (c < H) ? b1[c] : b2[c - H];
        } else {
            long i = id - per - 2 * H;
            xb[i] = f2bf(x[i]);
        }
    }
}

// Fused RGCN layer, edge-parallel aggregation:
// Phase 1: block owns contiguous edge range of its 32 dsts; 32 16-lane groups
//   consume it round-robin. Per edge: 1 packed dword, 1 coalesced 256B x-row
//   load, 8 ds_add_f32 into aggF[dloc][r*128+c]. Depth-2/3 register prefetch
//   pipeline hides the packed->x load chain. No per-dst serialization.
// Convert: fp32 aggF * inv -> bf16 aggB in place (read-all / barrier / write-all).
// Phase 2: out[32x128] = aggB[32x1024] @ W[rels] + x[d] @ root, MFMA, W from L2.
// Epilogue: +bias, relu?, coalesced store via LDS fp32 staging.
__global__ __launch_bounds__(512, 1) void layer_kernel(const unsigned short* __restrict__ xin,
                                                       const unsigned short* __restrict__ WTa,
                                                       const float* __restrict__ biasP,
                                                       const float* __restrict__ inv,
                                                       const int* __restrict__ rowptr,
                                                       const int* __restrict__ packed,
                                                       float* __restrict__ outf,
                                                       unsigned short* __restrict__ outb,
                                                       int N, int relu) {
    __shared__ __align__(16) float aggF[MT * SF];   // 131.6 KB, 1 block/CU
    __shared__ float invS[MT * RREL];
    const int t = threadIdx.x;
    const int Mbase = blockIdx.x * MT;
    const f32x4 fz = {0.f, 0.f, 0.f, 0.f};

    // zero payload (pads never read)
#pragma unroll
    for (int i = 0; i < 16; ++i) {
        int p = i * 2048 + t * 4;
        int row = p >> 10, wi = p & 1023;
        *(f32x4*)&aggF[row * SF + wi] = fz;
    }
    if (t < MT * RREL) {
        int dd = Mbase + (t >> 3);
        invS[t] = (dd < N) ? inv[(size_t)Mbase * RREL + t] : 1.0f;
    }
    int dend = Mbase + MT; if (dend > N) dend = N;
    const int ebeg = rowptr[Mbase];
    const int eend = rowptr[dend];
    __syncthreads();

    // -------- Phase 1: edge-parallel atomic aggregation --------
    const int g = t >> 4, fl = t & 15;
    if (eend > ebeg) {
        const int ecl = eend - 1;
        int iA = ebeg + g, iB = iA + 32, iC = iB + 32;
        int pkA = packed[iA <= ecl ? iA : ecl];
        int pkB = packed[iB <= ecl ? iB : ecl];
        int pkC = packed[iC <= ecl ? iC : ecl];
        u16x8 xvA = *(const u16x8*)&xin[(size_t)(pkA & 0xFFFFF) * H + fl * 8];
        u16x8 xvB = *(const u16x8*)&xin[(size_t)(pkB & 0xFFFFF) * H + fl * 8];
        while (iA < eend) {
            u16x8 xvC = *(const u16x8*)&xin[(size_t)(pkC & 0xFFFFF) * H + fl * 8];
            int iD = iC + 32;
            int pkD = packed[iD <= ecl ? iD : ecl];
            {
                int r = (pkA >> 20) & 7, dl = (pkA >> 23) & 31;
                float* dp = &aggF[dl * SF + r * H + fl * 8];
#pragma unroll
                for (int k = 0; k < 8; ++k) {
                    int j = (fl + k) & 7;   // rotate: spread banks within group
                    atomicAdd(&dp[j], bf2f((unsigned short)xvA[j]));
                }
            }
            iA = iB; iB = iC; iC = iD;
            pkA = pkB; pkB = pkC; pkC = pkD;
            xvA = xvB; xvB = xvC;
        }
    }
    __syncthreads();

    // -------- Convert: fp32 * inv -> bf16, in place --------
    u16x4 cc[16];
#pragma unroll
    for (int i = 0; i < 16; ++i) {
        int p = i * 2048 + t * 4;
        int row = p >> 10, wi = p & 1023;
        f32x4 v = *(const f32x4*)&aggF[row * SF + wi];
        float sc = invS[(row << 3) + (wi >> 7)];
#pragma unroll
        for (int j = 0; j < 4; ++j) cc[i][j] = f2bf(v[j] * sc);
    }
    __syncthreads();
    unsigned short* aggB = (unsigned short*)aggF;
#pragma unroll
    for (int i = 0; i < 16; ++i) {
        int p = i * 2048 + t * 4;
        int row = p >> 10, wi = p & 1023;
        *(u16x4*)&aggB[row * SB + wi] = cc[i];
    }
    __syncthreads();

    // -------- Phase 2: MFMA transform --------
    const int l = t & 63, w = t >> 6;
    const int colb = l & 15, quad = l >> 4;
    const int fcol = w * 16 + colb;
    f32x4 acc0 = fz, acc1 = fz;
    const unsigned short* arow0 = &aggB[colb * SB];
    const unsigned short* arow1 = &aggB[(16 + colb) * SB];
#pragma unroll
    for (int j = 0; j < RREL; ++j) {
#pragma unroll
        for (int ks = 0; ks < 4; ++ks) {
            const int kl = ks * 32 + quad * 8;
            bf16x8 b = *(const bf16x8*)&WTa[((size_t)j * H + fcol) * H + kl];
            bf16x8 a0 = *(const bf16x8*)&arow0[j * H + kl];
            bf16x8 a1 = *(const bf16x8*)&arow1[j * H + kl];
            acc0 = __builtin_amdgcn_mfma_f32_16x16x32_bf16(a0, b, acc0, 0, 0, 0);
            acc1 = __builtin_amdgcn_mfma_f32_16x16x32_bf16(a1, b, acc1, 0, 0, 0);
        }
    }
    {   // root term: A rows straight from global x
        int r0 = Mbase + colb;      if (r0 > N - 1) r0 = N - 1;
        int r1 = Mbase + 16 + colb; if (r1 > N - 1) r1 = N - 1;
        const unsigned short* x0 = &xin[(size_t)r0 * H];
        const unsigned short* x1 = &xin[(size_t)r1 * H];
#pragma unroll
        for (int ks = 0; ks < 4; ++ks) {
            const int kl = ks * 32 + quad * 8;
            bf16x8 b = *(const bf16x8*)&WTa[((size_t)RREL * H + fcol) * H + kl];
            bf16x8 a0 = *(const bf16x8*)&x0[kl];
            bf16x8 a1 = *(const bf16x8*)&x1[kl];
            acc0 = __builtin_amdgcn_mfma_f32_16x16x32_bf16(a0, b, acc0, 0, 0, 0);
            acc1 = __builtin_amdgcn_mfma_f32_16x16x32_bf16(a1, b, acc1, 0, 0, 0);
        }
    }

    __syncthreads();  // all aggB reads done; reuse LDS as fp32 staging [32][132]
    float* stg = (float*)aggF;
    const float bcol = biasP[fcol];
#pragma unroll
    for (int i = 0; i < 4; ++i) {
        float v0 = acc0[i] + bcol;
        float v1 = acc1[i] + bcol;
        if (relu) { v0 = fmaxf(v0, 0.f); v1 = fmaxf(v1, 0.f); }
        stg[(quad * 4 + i) * 132 + fcol] = v0;
        stg[(16 + quad * 4 + i) * 132 + fcol] = v1;
    }
    __syncthreads();
    {
        int row = t >> 4;           // 0..31
        int dd = Mbase + row;
        if (dd < N) {
            int c0 = fl * 8;
            f32x4 p0 = *(const f32x4*)&stg[row * 132 + c0];
            f32x4 p1 = *(const f32x4*)&stg[row * 132 + c0 + 4];
            if (outf) {
                *(f32x4*)&outf[(size_t)dd * H + c0] = p0;
                *(f32x4*)&outf[(size_t)dd * H + c0 + 4] = p1;
            } else {
                u16x8 o;
#pragma unroll
                for (int j = 0; j < 4; ++j) { o[j] = f2bf(p0[j]); o[4 + j] = f2bf(p1[j]); }
                *(u16x8*)&outb[(size_t)dd * H + c0] = o;
            }
        }
    }
}

extern "C" void kernel_launch(void* const* d_in, const int* in_sizes, int n_in,
                              void* d_out, int out_size, void* d_ws, size_t ws_size,
                              hipStream_t stream) {
    const int* edge_index = (const int*)d_in[0];
    const int* edge_type  = (const int*)d_in[1];
    const float* node_emb = (const float*)d_in[2];
    const float* W1    = (const float*)d_in[3];
    const float* root1 = (const float*)d_in[4];
    const float* b1    = (const float*)d_in[5];
    const float* W2    = (const float*)d_in[6];
    const float* root2 = (const float*)d_in[7];
    const float* b2    = (const float*)d_in[8];
    float* out = (float*)d_out;

    const int E = in_sizes[1];
    const int N = in_sizes[2] / H;

    char* base = (char*)d_ws;
    size_t off = 0;
    auto take = [&](size_t bytes) { size_t o = off; off = (off + bytes + 63) & ~(size_t)63; return o; };
    int*   cnt     = (int*)  (base + take((size_t)N * RREL * 4));
    int*   cursor8 = (int*)  (base + take((size_t)N * RREL * 4));  // adjacent to cnt: single zero pass
    int*   rploc   = (int*)  (base + take((size_t)N * 4));
    int*   bsum    = (int*)  (base + take(256 * 4));
    int*   rowptr  = (int*)  (base + take(((size_t)N + 1) * 4));
    int*   rowptr2 = (int*)  (base + take((size_t)N * RREL * 4));
    float* inv     = (float*)(base + take((size_t)N * RREL * 4));
    int*   packed  = (int*)  (base + take((size_t)E * 4));
    unsigned short* WTa1 = (unsigned short*)(base + take((size_t)NJ * H * H * 2));
    unsigned short* WTa2 = (unsigned short*)(base + take((size_t)NJ * H * H * 2));
    float* biasP   = (float*)(base + take(2 * H * 4));
    unsigned short* xb  = (unsigned short*)(base + take((size_t)N * H * 2));
    unsigned short* hb  = (unsigned short*)(base + take((size_t)N * H * 2));
    (void)ws_size;

    const int nbScan = (N + 255) / 256;

    zero_kernel<<<512, 256, 0, stream>>>(cnt, (long)N * (2 * RREL));  // cnt + cursor8
    count_kernel<<<(E + 255) / 256, 256, 0, stream>>>(edge_index, edge_type, cnt, E);
    scan_block_kernel<<<nbScan, 256, 0, stream>>>(cnt, rploc, bsum, N);
    finalize_kernel<<<nbScan, 256, 0, stream>>>(cnt, rploc, bsum, rowptr, rowptr2, inv, N, nbScan);
    fill_kernel<<<(E + 255) / 256, 256, 0, stream>>>(edge_index, edge_type, cursor8, rowptr2, packed, E);
    wcat_tobf_kernel<<<2048, 256, 0, stream>>>(W1, root1, W2, root2, b1, b2,
                                               WTa1, WTa2, biasP, node_emb, xb, (long)N * H);

    const int gl = (N + MT - 1) / MT;
    layer_kernel<<<gl, 512, 0, stream>>>(xb, WTa1, biasP, inv, rowptr, packed,
                                         nullptr, hb, N, 1);
    layer_kernel<<<gl, 512, 0, stream>>>(hb, WTa2, biasP + H, inv, rowptr, packed,
                                         out, nullptr, N, 0);
}

// Round 4
// 1209.579 us; speedup vs baseline: 1.0011x; 1.0011x over previous
//
#include <hip/hip_runtime.h>

#define H 128
#define RREL 8
#define NJ 9        // 8 relations + root
#define MT 32       // dsts per layer-block
#define SF 1028     // fp32 agg row stride (floats): 16B-aligned, +4-dword bank spread per row
#define SB 1032     // bf16 agg row stride (shorts)

typedef short bf16x8 __attribute__((ext_vector_type(8)));
typedef float f32x4 __attribute__((ext_vector_type(4)));
typedef unsigned short u16x8 __attribute__((ext_vector_type(8)));
typedef unsigned short u16x4 __attribute__((ext_vector_type(4)));

static __device__ __forceinline__ unsigned short f2bf(float f) {
    unsigned int u = __float_as_uint(f);
    unsigned int r = (u + 0x7fffu + ((u >> 16) & 1u)) >> 16;
    return (unsigned short)r;
}
static __device__ __forceinline__ float bf2f(unsigned short u) {
    return __uint_as_float(((unsigned int)u) << 16);
}
// native no-return LDS fp32 atomic add (avoids the CAS loop hipcc emits for
// atomicAdd on shared floats without unsafe-fp-atomics)
static __device__ __forceinline__ void lds_fadd(const float* p, float v) {
    unsigned off = (unsigned)(unsigned long long)p;  // low 32b of shared ptr = LDS offset
    asm volatile("ds_add_f32 %0, %1" :: "v"(off), "v"(v) : "memory");
}

__global__ void zero_kernel(int* p, long n) {
    long i = (long)blockIdx.x * blockDim.x + threadIdx.x;
    long stride = (long)gridDim.x * blockDim.x;
    for (; i < n; i += stride) p[i] = 0;
}

__global__ void count_kernel(const int* __restrict__ ei, const int* __restrict__ et,
                             int* __restrict__ cnt, int E) {
    int e = blockIdx.x * 256 + threadIdx.x;
    if (e >= E) return;
    int d = ei[E + e];
    int r = et[e];
    atomicAdd(&cnt[(size_t)d * RREL + r], 1);
}

__global__ void scan_block_kernel(const int* __restrict__ cnt, int* __restrict__ rploc,
                                  int* __restrict__ bsum, int N) {
    __shared__ int s[256];
    int t = threadIdx.x;
    int d = blockIdx.x * 256 + t;
    int v = 0;
    if (d < N) {
#pragma unroll
        for (int r = 0; r < RREL; ++r) v += cnt[(size_t)d * RREL + r];
    }
    s[t] = v;
    __syncthreads();
#pragma unroll
    for (int off = 1; off < 256; off <<= 1) {
        int u = 0;
        if (t >= off) u = s[t - off];
        __syncthreads();
        s[t] += u;
        __syncthreads();
    }
    if (d < N) rploc[d] = s[t] - v;
    if (t == 255) bsum[blockIdx.x] = s[255];
}

// finalize with inlined top-level scan of bsum (nb <= 256).
__global__ void finalize_kernel(const int* __restrict__ cnt, const int* __restrict__ rploc,
                                const int* __restrict__ bsum, int* __restrict__ rowptr,
                                int* __restrict__ rowptr2, float* __restrict__ inv,
                                int N, int nb) {
    __shared__ int s[256];
    int t = threadIdx.x;
    int v = (t < nb) ? bsum[t] : 0;
    s[t] = v;
    __syncthreads();
#pragma unroll
    for (int off = 1; off < 256; off <<= 1) {
        int u = 0;
        if (t >= off) u = s[t - off];
        __syncthreads();
        s[t] += u;
        __syncthreads();
    }
    int boffB = (blockIdx.x == 0) ? 0 : s[blockIdx.x - 1];
    int d = blockIdx.x * 256 + t;
    if (d >= N) return;
    int rp = rploc[d] + boffB;
    rowptr[d] = rp;
    int run = rp;
#pragma unroll
    for (int r = 0; r < RREL; ++r) {
        int c = cnt[(size_t)d * RREL + r];
        rowptr2[(size_t)d * RREL + r] = run;
        inv[(size_t)d * RREL + r] = 1.0f / (float)max(c, 1);
        run += c;
    }
    if (d == N - 1) rowptr[N] = run;
}

// packed[pos] = src | (rel<<20) | (dloc<<23), binned by (dst, rel)
__global__ void fill_kernel(const int* __restrict__ ei, const int* __restrict__ et,
                            int* __restrict__ cursor, const int* __restrict__ rowptr2,
                            int* __restrict__ packed, int E) {
    int e = blockIdx.x * 256 + threadIdx.x;
    if (e >= E) return;
    int d = ei[E + e];
    int r = et[e];
    size_t bin = (size_t)d * RREL + r;
    int pos = rowptr2[bin] + atomicAdd(&cursor[bin], 1);
    packed[pos] = ei[e] | (r << 20) | ((d & (MT - 1)) << 23);
}

// Fused weight prep + x->bf16 conversion (grid-stride over both ranges).
__global__ void wcat_tobf_kernel(const float* __restrict__ W1, const float* __restrict__ r1,
                                 const float* __restrict__ W2, const float* __restrict__ r2,
                                 const float* __restrict__ b1, const float* __restrict__ b2,
                                 unsigned short* __restrict__ WTa1, unsigned short* __restrict__ WTa2,
                                 float* __restrict__ biasP,
                                 const float* __restrict__ x, unsigned short* __restrict__ xb,
                                 long nx) {
    const long per = (long)NJ * H * H;
    const long total = per + 2 * H + nx;
    for (long id = (long)blockIdx.x * 256 + threadIdx.x; id < total; id += (long)gridDim.x * 256) {
        if (id < per) {
            int j = (int)(id / (H * H));
            int fk = (int)(id - (long)j * (H * H));
            int f = fk >> 7, k = fk & 127;
            float v1 = (j < RREL) ? W1[((size_t)j * H + k) * H + f] : r1[(size_t)k * H + f];
            WTa1[id] = f2bf(v1);
            float v2 = (j < RREL) ? W2[((size_t)j * H + k) * H + f] : r2[(size_t)k * H + f];
            WTa2[id] = f2bf(v2);
        } else if (id < per + 2 * H) {
            int c = (int)(id - per);
            biasP[c] = (c < H) ? b1[c] : b2[c - H];
        } else {
            long i = id - per - 2 * H;
            xb[i] = f2bf(x[i]);
        }
    }
}

// Fused RGCN layer, edge-parallel aggregation with NATIVE ds_add_f32.
__global__ __launch_bounds__(512, 1) void layer_kernel(const unsigned short* __restrict__ xin,
                                                       const unsigned short* __restrict__ WTa,
                                                       const float* __restrict__ biasP,
                                                       const float* __restrict__ inv,
                                                       const int* __restrict__ rowptr,
                                                       const int* __restrict__ packed,
                                                       float* __restrict__ outf,
                                                       unsigned short* __restrict__ outb,
                                                       int N, int relu) {
    __shared__ __align__(16) float aggF[MT * SF];   // 131.6 KB, 1 block/CU
    __shared__ float invS[MT * RREL];
    const int t = threadIdx.x;
    const int Mbase = blockIdx.x * MT;
    const f32x4 fz = {0.f, 0.f, 0.f, 0.f};

    // zero payload (pads never read)
#pragma unroll
    for (int i = 0; i < 16; ++i) {
        int p = i * 2048 + t * 4;
        int row = p >> 10, wi = p & 1023;
        *(f32x4*)&aggF[row * SF + wi] = fz;
    }
    if (t < MT * RREL) {
        int dd = Mbase + (t >> 3);
        invS[t] = (dd < N) ? inv[(size_t)Mbase * RREL + t] : 1.0f;
    }
    int dend = Mbase + MT; if (dend > N) dend = N;
    const int ebeg = rowptr[Mbase];
    const int eend = rowptr[dend];
    __syncthreads();

    // -------- Phase 1: edge-parallel native-atomic aggregation --------
    const int g = t >> 4, fl = t & 15;
    const int rot = (fl >> 2) << 1;   // per-instr 16 lanes -> 16 distinct banks
    if (eend > ebeg) {
        const int ecl = eend - 1;
        int iA = ebeg + g, iB = iA + 32, iC = iB + 32;
        int pkA = packed[iA <= ecl ? iA : ecl];
        int pkB = packed[iB <= ecl ? iB : ecl];
        int pkC = packed[iC <= ecl ? iC : ecl];
        u16x8 xvA = *(const u16x8*)&xin[(size_t)(pkA & 0xFFFFF) * H + fl * 8];
        u16x8 xvB = *(const u16x8*)&xin[(size_t)(pkB & 0xFFFFF) * H + fl * 8];
        while (iA < eend) {
            u16x8 xvC = *(const u16x8*)&xin[(size_t)(pkC & 0xFFFFF) * H + fl * 8];
            int iD = iC + 32;
            int pkD = packed[iD <= ecl ? iD : ecl];
            {
                int r = (pkA >> 20) & 7, dl = (pkA >> 23) & 31;
                const float* dp = &aggF[dl * SF + r * H + fl * 8];
#pragma unroll
                for (int k = 0; k < 8; ++k) {
                    int j = (k + rot) & 7;
                    lds_fadd(dp + j, bf2f((unsigned short)xvA[j]));
                }
            }
            iA = iB; iB = iC; iC = iD;
            pkA = pkB; pkB = pkC; pkC = pkD;
            xvA = xvB; xvB = xvC;
        }
    }
    __syncthreads();

    // -------- Convert: fp32 * inv -> bf16, in place --------
    u16x4 cc[16];
#pragma unroll
    for (int i = 0; i < 16; ++i) {
        int p = i * 2048 + t * 4;
        int row = p >> 10, wi = p & 1023;
        f32x4 v = *(const f32x4*)&aggF[row * SF + wi];
        float sc = invS[(row << 3) + (wi >> 7)];
#pragma unroll
        for (int j = 0; j < 4; ++j) cc[i][j] = f2bf(v[j] * sc);
    }
    __syncthreads();
    unsigned short* aggB = (unsigned short*)aggF;
#pragma unroll
    for (int i = 0; i < 16; ++i) {
        int p = i * 2048 + t * 4;
        int row = p >> 10, wi = p & 1023;
        *(u16x4*)&aggB[row * SB + wi] = cc[i];
    }
    __syncthreads();

    // -------- Phase 2: MFMA transform --------
    const int l = t & 63, w = t >> 6;
    const int colb = l & 15, quad = l >> 4;
    const int fcol = w * 16 + colb;
    f32x4 acc0 = fz, acc1 = fz;
    const unsigned short* arow0 = &aggB[colb * SB];
    const unsigned short* arow1 = &aggB[(16 + colb) * SB];
#pragma unroll
    for (int j = 0; j < RREL; ++j) {
#pragma unroll
        for (int ks = 0; ks < 4; ++ks) {
            const int kl = ks * 32 + quad * 8;
            bf16x8 b = *(const bf16x8*)&WTa[((size_t)j * H + fcol) * H + kl];
            bf16x8 a0 = *(const bf16x8*)&arow0[j * H + kl];
            bf16x8 a1 = *(const bf16x8*)&arow1[j * H + kl];
            acc0 = __builtin_amdgcn_mfma_f32_16x16x32_bf16(a0, b, acc0, 0, 0, 0);
            acc1 = __builtin_amdgcn_mfma_f32_16x16x32_bf16(a1, b, acc1, 0, 0, 0);
        }
    }
    {   // root term: A rows straight from global x
        int r0 = Mbase + colb;      if (r0 > N - 1) r0 = N - 1;
        int r1 = Mbase + 16 + colb; if (r1 > N - 1) r1 = N - 1;
        const unsigned short* x0 = &xin[(size_t)r0 * H];
        const unsigned short* x1 = &xin[(size_t)r1 * H];
#pragma unroll
        for (int ks = 0; ks < 4; ++ks) {
            const int kl = ks * 32 + quad * 8;
            bf16x8 b = *(const bf16x8*)&WTa[((size_t)RREL * H + fcol) * H + kl];
            bf16x8 a0 = *(const bf16x8*)&x0[kl];
            bf16x8 a1 = *(const bf16x8*)&x1[kl];
            acc0 = __builtin_amdgcn_mfma_f32_16x16x32_bf16(a0, b, acc0, 0, 0, 0);
            acc1 = __builtin_amdgcn_mfma_f32_16x16x32_bf16(a1, b, acc1, 0, 0, 0);
        }
    }

    __syncthreads();  // all aggB reads done; reuse LDS as fp32 staging [32][132]
    float* stg = (float*)aggF;
    const float bcol = biasP[fcol];
#pragma unroll
    for (int i = 0; i < 4; ++i) {
        float v0 = acc0[i] + bcol;
        float v1 = acc1[i] + bcol;
        if (relu) { v0 = fmaxf(v0, 0.f); v1 = fmaxf(v1, 0.f); }
        stg[(quad * 4 + i) * 132 + fcol] = v0;
        stg[(16 + quad * 4 + i) * 132 + fcol] = v1;
    }
    __syncthreads();
    {
        int row = t >> 4;           // 0..31
        int dd = Mbase + row;
        if (dd < N) {
            int c0 = fl * 8;
            f32x4 p0 = *(const f32x4*)&stg[row * 132 + c0];
            f32x4 p1 = *(const f32x4*)&stg[row * 132 + c0 + 4];
            if (outf) {
                *(f32x4*)&outf[(size_t)dd * H + c0] = p0;
                *(f32x4*)&outf[(size_t)dd * H + c0 + 4] = p1;
            } else {
                u16x8 o;
#pragma unroll
                for (int j = 0; j < 4; ++j) { o[j] = f2bf(p0[j]); o[4 + j] = f2bf(p1[j]); }
                *(u16x8*)&outb[(size_t)dd * H + c0] = o;
            }
        }
    }
}

extern "C" void kernel_launch(void* const* d_in, const int* in_sizes, int n_in,
                              void* d_out, int out_size, void* d_ws, size_t ws_size,
                              hipStream_t stream) {
    const int* edge_index = (const int*)d_in[0];
    const int* edge_type  = (const int*)d_in[1];
    const float* node_emb = (const float*)d_in[2];
    const float* W1    = (const float*)d_in[3];
    const float* root1 = (const float*)d_in[4];
    const float* b1    = (const float*)d_in[5];
    const float* W2    = (const float*)d_in[6];
    const float* root2 = (const float*)d_in[7];
    const float* b2    = (const float*)d_in[8];
    float* out = (float*)d_out;

    const int E = in_sizes[1];
    const int N = in_sizes[2] / H;

    char* base = (char*)d_ws;
    size_t off = 0;
    auto take = [&](size_t bytes) { size_t o = off; off = (off + bytes + 63) & ~(size_t)63; return o; };
    int*   cnt     = (int*)  (base + take((size_t)N * RREL * 4));
    int*   cursor8 = (int*)  (base + take((size_t)N * RREL * 4));  // adjacent to cnt: single zero pass
    int*   rploc   = (int*)  (base + take((size_t)N * 4));
    int*   bsum    = (int*)  (base + take(256 * 4));
    int*   rowptr  = (int*)  (base + take(((size_t)N + 1) * 4));
    int*   rowptr2 = (int*)  (base + take((size_t)N * RREL * 4));
    float* inv     = (float*)(base + take((size_t)N * RREL * 4));
    int*   packed  = (int*)  (base + take((size_t)E * 4));
    unsigned short* WTa1 = (unsigned short*)(base + take((size_t)NJ * H * H * 2));
    unsigned short* WTa2 = (unsigned short*)(base + take((size_t)NJ * H * H * 2));
    float* biasP   = (float*)(base + take(2 * H * 4));
    unsigned short* xb  = (unsigned short*)(base + take((size_t)N * H * 2));
    unsigned short* hb  = (unsigned short*)(base + take((size_t)N * H * 2));
    (void)ws_size;

    const int nbScan = (N + 255) / 256;

    zero_kernel<<<512, 256, 0, stream>>>(cnt, (long)N * (2 * RREL));  // cnt + cursor8
    count_kernel<<<(E + 255) / 256, 256, 0, stream>>>(edge_index, edge_type, cnt, E);
    scan_block_kernel<<<nbScan, 256, 0, stream>>>(cnt, rploc, bsum, N);
    finalize_kernel<<<nbScan, 256, 0, stream>>>(cnt, rploc, bsum, rowptr, rowptr2, inv, N, nbScan);
    fill_kernel<<<(E + 255) / 256, 256, 0, stream>>>(edge_index, edge_type, cursor8, rowptr2, packed, E);
    wcat_tobf_kernel<<<2048, 256, 0, stream>>>(W1, root1, W2, root2, b1, b2,
                                               WTa1, WTa2, biasP, node_emb, xb, (long)N * H);

    const int gl = (N + MT - 1) / MT;
    layer_kernel<<<gl, 512, 0, stream>>>(xb, WTa1, biasP, inv, rowptr, packed,
                                         nullptr, hb, N, 1);
    layer_kernel<<<gl, 512, 0, stream>>>(hb, WTa2, biasP + H, inv, rowptr, packed,
                                         out, nullptr, N, 0);
}

// Round 5
// 339.729 us; speedup vs baseline: 3.5643x; 3.5604x over previous
//
#include <hip/hip_runtime.h>

#define H 128
#define RREL 8
#define NJ 9        // 8 relations + root
#define MT 32       // dsts per layer-block
#define LROW 1160   // agg LDS row stride in elems (1152 + 8 pad; 2320B = 145*16B)

typedef short bf16x8 __attribute__((ext_vector_type(8)));
typedef float f32x4 __attribute__((ext_vector_type(4)));
typedef unsigned short u16x8 __attribute__((ext_vector_type(8)));

static __device__ __forceinline__ unsigned short f2bf(float f) {
    unsigned int u = __float_as_uint(f);
    unsigned int r = (u + 0x7fffu + ((u >> 16) & 1u)) >> 16;
    return (unsigned short)r;
}
static __device__ __forceinline__ float bf2f(unsigned short u) {
    return __uint_as_float(((unsigned int)u) << 16);
}

__global__ void zero_kernel(int* p, long n) {
    long i = (long)blockIdx.x * blockDim.x + threadIdx.x;
    long stride = (long)gridDim.x * blockDim.x;
    for (; i < n; i += stride) p[i] = 0;
}

__global__ void count_kernel(const int* __restrict__ ei, const int* __restrict__ et,
                             int* __restrict__ cnt, int E) {
    int e = blockIdx.x * 256 + threadIdx.x;
    if (e >= E) return;
    int d = ei[E + e];
    int r = et[e];
    atomicAdd(&cnt[(size_t)d * RREL + r], 1);
}

__global__ void scan_block_kernel(const int* __restrict__ cnt, int* __restrict__ rploc,
                                  int* __restrict__ bsum, int N) {
    __shared__ int s[256];
    int t = threadIdx.x;
    int d = blockIdx.x * 256 + t;
    int v = 0;
    if (d < N) {
#pragma unroll
        for (int r = 0; r < RREL; ++r) v += cnt[(size_t)d * RREL + r];
    }
    s[t] = v;
    __syncthreads();
#pragma unroll
    for (int off = 1; off < 256; off <<= 1) {
        int u = 0;
        if (t >= off) u = s[t - off];
        __syncthreads();
        s[t] += u;
        __syncthreads();
    }
    if (d < N) rploc[d] = s[t] - v;
    if (t == 255) bsum[blockIdx.x] = s[255];
}

// finalize with inlined top-level scan of bsum (nb <= 256).
// rowptr[d] = dst-bin start; rowptr2[d*8+r] = (dst,rel)-subbin start; inv = 1/max(cnt,1)
__global__ void finalize_kernel(const int* __restrict__ cnt, const int* __restrict__ rploc,
                                const int* __restrict__ bsum, int* __restrict__ rowptr,
                                int* __restrict__ rowptr2, float* __restrict__ inv,
                                int N, int nb) {
    __shared__ int s[256];
    int t = threadIdx.x;
    int v = (t < nb) ? bsum[t] : 0;
    s[t] = v;
    __syncthreads();
#pragma unroll
    for (int off = 1; off < 256; off <<= 1) {
        int u = 0;
        if (t >= off) u = s[t - off];
        __syncthreads();
        s[t] += u;
        __syncthreads();
    }
    int boffB = (blockIdx.x == 0) ? 0 : s[blockIdx.x - 1];
    int d = blockIdx.x * 256 + t;
    if (d >= N) return;
    int rp = rploc[d] + boffB;
    rowptr[d] = rp;
    int run = rp;
#pragma unroll
    for (int r = 0; r < RREL; ++r) {
        int c = cnt[(size_t)d * RREL + r];
        rowptr2[(size_t)d * RREL + r] = run;
        inv[(size_t)d * RREL + r] = 1.0f / (float)max(c, 1);
        run += c;
    }
    if (d == N - 1) rowptr[N] = run;
}

// packed[pos] = src | (rel<<20), binned by (dst, rel) -> rel-sorted within each dst bin
__global__ void fill_kernel(const int* __restrict__ ei, const int* __restrict__ et,
                            int* __restrict__ cursor, const int* __restrict__ rowptr2,
                            int* __restrict__ packed, int E) {
    int e = blockIdx.x * 256 + threadIdx.x;
    if (e >= E) return;
    int d = ei[E + e];
    int r = et[e];
    size_t bin = (size_t)d * RREL + r;
    int pos = rowptr2[bin] + atomicAdd(&cursor[bin], 1);
    packed[pos] = ei[e] | (r << 20);
}

// Fused weight prep + x->bf16 conversion (grid-stride over both ranges).
// WTa[j][f][k] = W[j][k][f] (j<8) or root[k][f] (j==8); bias natural order.
__global__ void wcat_tobf_kernel(const float* __restrict__ W1, const float* __restrict__ r1,
                                 const float* __restrict__ W2, const float* __restrict__ r2,
                                 const float* __restrict__ b1, const float* __restrict__ b2,
                                 unsigned short* __restrict__ WTa1, unsigned short* __restrict__ WTa2,
                                 float* __restrict__ biasP,
                                 const float* __restrict__ x, unsigned short* __restrict__ xb,
                                 long nx) {
    const long per = (long)NJ * H * H;
    const long total = per + 2 * H + nx;
    for (long id = (long)blockIdx.x * 256 + threadIdx.x; id < total; id += (long)gridDim.x * 256) {
        if (id < per) {
            int j = (int)(id / (H * H));
            int fk = (int)(id - (long)j * (H * H));
            int f = fk >> 7, k = fk & 127;
            float v1 = (j < RREL) ? W1[((size_t)j * H + k) * H + f] : r1[(size_t)k * H + f];
            WTa1[id] = f2bf(v1);
            float v2 = (j < RREL) ? W2[((size_t)j * H + k) * H + f] : r2[(size_t)k * H + f];
            WTa2[id] = f2bf(v2);
        } else if (id < per + 2 * H) {
            int c = (int)(id - per);
            biasP[c] = (c < H) ? b1[c] : b2[c - H];
        } else {
            long i = id - per - 2 * H;
            xb[i] = f2bf(x[i]);
        }
    }
}

// accumulate one edge (branchless, rel-sorted, flush-every-edge: last write per
// (d,r) slot is the full sum; clamped tail dups add 0 and rewrite same value)
#define ACC(EE, XV, VV)                                                        \
    do {                                                                       \
        int r_ = ((VV) >> 20) & 7;                                             \
        bool nr_ = (r_ != rcur);                                               \
        float ivc_ = __shfl(ivl, gbase + r_);                                  \
        bool pr_ = (hb + (EE)) < m;                                            \
        u16x8 o_;                                                              \
        _Pragma("unroll")                                                      \
        for (int j = 0; j < 8; ++j) {                                          \
            float xx_ = bf2f((unsigned short)(XV)[j]);                         \
            float t0_ = nr_ ? 0.f : tmp[j];                                    \
            tmp[j] = t0_ + (pr_ ? xx_ : 0.f);                                  \
            o_[j] = f2bf(ivc_ * tmp[j]);                                       \
        }                                                                      \
        *(u16x8*)&rowp[r_ * H + kc] = o_;                                      \
        rcur = r_;                                                             \
    } while (0)

// Fused RGCN layer: aggregate-then-transform.
// Phase 1: per dst (one 16-lane group), rel-sorted edge walk. 8-edge load
//   batches in NAMED registers + sched_barrier(0) pin so all 8 stay in flight
//   (round-2's array version let the scheduler sink loads: VGPR=52 proved it).
// Phase 2: out[32x128] = agg[32x1152] @ Wcat[1152x128] via MFMA, W from L2.
// Epilogue: +bias, relu?, coalesced store via LDS fp32 staging.
__global__ __launch_bounds__(512) void layer_kernel(const unsigned short* __restrict__ xin,
                                                    const unsigned short* __restrict__ WTa,
                                                    const float* __restrict__ biasP,
                                                    const float* __restrict__ inv,
                                                    const int* __restrict__ rowptr,
                                                    const int* __restrict__ packed,
                                                    float* __restrict__ outf,
                                                    unsigned short* __restrict__ outb,
                                                    int N, int relu) {
    __shared__ __align__(16) unsigned short aggS[MT * LROW];
    const int t = threadIdx.x;
    const int l = t & 63;
    const int w = t >> 6;           // wave 0..7
    const int g16 = t >> 4;         // group (dst) 0..31
    const int fl = t & 15;
    const int kc = fl * 8;
    const int gbase = l & 48;
    const int Mbase = blockIdx.x * MT;
    const int d = Mbase + g16;
    const bool valid = d < N;

    unsigned short* rowp = &aggS[g16 * LROW];
    {
        u16x8 z = {0, 0, 0, 0, 0, 0, 0, 0};
#pragma unroll
        for (int c = 0; c < 8; ++c) *(u16x8*)&rowp[(c * 16 + fl) * 8] = z;  // zero rel slots
        if (valid) {  // root slot j=8: x[d] itself (coefficient 1)
            *(u16x8*)&rowp[RREL * H + kc] = *(const u16x8*)&xin[(size_t)d * H + kc];
        } else {
            *(u16x8*)&rowp[RREL * H + kc] = z;
        }
    }

    int rp = 0;
    if (valid && fl < 2) rp = rowptr[d + fl];
    float ivl = 0.f;
    if (valid && fl < 8) ivl = inv[(size_t)d * RREL + fl];
    int beg = __shfl(rp, gbase);
    int end = __shfl(rp, gbase + 1);

    if (end > beg) {
        float tmp[8] = {};
        int rcur = 100;  // sentinel: first real edge always resets
        int idx0 = beg + fl; if (idx0 > end - 1) idx0 = end - 1;
        int pk = packed[idx0];
        for (int i = beg; i < end; i += 16) {
            // prefetch next chunk's packed dword
            int ni = i + 16 + fl; if (ni > end - 1) ni = end - 1;
            int pkN = packed[ni];
            int m = end - i;
            if (m > 16) m = 16;
#pragma unroll
            for (int half = 0; half < 2; ++half) {
                const int hb = half * 8;
                int v0 = __shfl(pk, gbase + hb + 0);
                int v1 = __shfl(pk, gbase + hb + 1);
                int v2 = __shfl(pk, gbase + hb + 2);
                int v3 = __shfl(pk, gbase + hb + 3);
                int v4 = __shfl(pk, gbase + hb + 4);
                int v5 = __shfl(pk, gbase + hb + 5);
                int v6 = __shfl(pk, gbase + hb + 6);
                int v7 = __shfl(pk, gbase + hb + 7);
                u16x8 x0 = *(const u16x8*)&xin[(size_t)(v0 & 0xFFFFF) * H + kc];
                u16x8 x1 = *(const u16x8*)&xin[(size_t)(v1 & 0xFFFFF) * H + kc];
                u16x8 x2 = *(const u16x8*)&xin[(size_t)(v2 & 0xFFFFF) * H + kc];
                u16x8 x3 = *(const u16x8*)&xin[(size_t)(v3 & 0xFFFFF) * H + kc];
                u16x8 x4 = *(const u16x8*)&xin[(size_t)(v4 & 0xFFFFF) * H + kc];
                u16x8 x5 = *(const u16x8*)&xin[(size_t)(v5 & 0xFFFFF) * H + kc];
                u16x8 x6 = *(const u16x8*)&xin[(size_t)(v6 & 0xFFFFF) * H + kc];
                u16x8 x7 = *(const u16x8*)&xin[(size_t)(v7 & 0xFFFFF) * H + kc];
                __builtin_amdgcn_sched_barrier(0);  // pin: 8 loads issued before accumulate
                ACC(0, x0, v0);
                ACC(1, x1, v1);
                ACC(2, x2, v2);
                ACC(3, x3, v3);
                ACC(4, x4, v4);
                ACC(5, x5, v5);
                ACC(6, x6, v6);
                ACC(7, x7, v7);
            }
            pk = pkN;
        }
    }

    __syncthreads();

    // Phase 2: wave w owns output cols [w*16, w*16+16), both 16-row halves.
    const int colb = l & 15, quad = l >> 4;
    const int fcol = w * 16 + colb;
    const f32x4 fz = {0.f, 0.f, 0.f, 0.f};
    f32x4 acc0 = fz, acc1 = fz;
    const unsigned short* arow0 = &aggS[colb * LROW];
    const unsigned short* arow1 = &aggS[(16 + colb) * LROW];
#pragma unroll
    for (int j = 0; j < NJ; ++j) {
#pragma unroll
        for (int ks = 0; ks < 4; ++ks) {
            const int kl = ks * 32 + quad * 8;
            bf16x8 b = *(const bf16x8*)&WTa[((size_t)j * H + fcol) * H + kl];
            bf16x8 a0 = *(const bf16x8*)&arow0[j * H + kl];
            bf16x8 a1 = *(const bf16x8*)&arow1[j * H + kl];
            acc0 = __builtin_amdgcn_mfma_f32_16x16x32_bf16(a0, b, acc0, 0, 0, 0);
            acc1 = __builtin_amdgcn_mfma_f32_16x16x32_bf16(a1, b, acc1, 0, 0, 0);
        }
    }

    __syncthreads();  // all aggS reads done; reuse as fp32 staging [32][132]
    float* stg = (float*)aggS;
    const float bcol = biasP[fcol];
#pragma unroll
    for (int i = 0; i < 4; ++i) {
        float v0 = acc0[i] + bcol;
        float v1 = acc1[i] + bcol;
        if (relu) { v0 = fmaxf(v0, 0.f); v1 = fmaxf(v1, 0.f); }
        stg[(quad * 4 + i) * 132 + fcol] = v0;
        stg[(16 + quad * 4 + i) * 132 + fcol] = v1;
    }
    __syncthreads();
    {
        int row = t >> 4;           // 0..31
        int dd = Mbase + row;
        if (dd < N) {
            int c0 = fl * 8;
            f32x4 p0 = *(const f32x4*)&stg[row * 132 + c0];
            f32x4 p1 = *(const f32x4*)&stg[row * 132 + c0 + 4];
            if (outf) {
                *(f32x4*)&outf[(size_t)dd * H + c0] = p0;
                *(f32x4*)&outf[(size_t)dd * H + c0 + 4] = p1;
            } else {
                u16x8 o;
#pragma unroll
                for (int j = 0; j < 4; ++j) { o[j] = f2bf(p0[j]); o[4 + j] = f2bf(p1[j]); }
                *(u16x8*)&outb[(size_t)dd * H + c0] = o;
            }
        }
    }
}

extern "C" void kernel_launch(void* const* d_in, const int* in_sizes, int n_in,
                              void* d_out, int out_size, void* d_ws, size_t ws_size,
                              hipStream_t stream) {
    const int* edge_index = (const int*)d_in[0];
    const int* edge_type  = (const int*)d_in[1];
    const float* node_emb = (const float*)d_in[2];
    const float* W1    = (const float*)d_in[3];
    const float* root1 = (const float*)d_in[4];
    const float* b1    = (const float*)d_in[5];
    const float* W2    = (const float*)d_in[6];
    const float* root2 = (const float*)d_in[7];
    const float* b2    = (const float*)d_in[8];
    float* out = (float*)d_out;

    const int E = in_sizes[1];
    const int N = in_sizes[2] / H;

    char* base = (char*)d_ws;
    size_t off = 0;
    auto take = [&](size_t bytes) { size_t o = off; off = (off + bytes + 63) & ~(size_t)63; return o; };
    int*   cnt     = (int*)  (base + take((size_t)N * RREL * 4));
    int*   cursor8 = (int*)  (base + take((size_t)N * RREL * 4));  // adjacent to cnt: single zero pass
    int*   rploc   = (int*)  (base + take((size_t)N * 4));
    int*   bsum    = (int*)  (base + take(256 * 4));
    int*   rowptr  = (int*)  (base + take(((size_t)N + 1) * 4));
    int*   rowptr2 = (int*)  (base + take((size_t)N * RREL * 4));
    float* inv     = (float*)(base + take((size_t)N * RREL * 4));
    int*   packed  = (int*)  (base + take((size_t)E * 4));
    unsigned short* WTa1 = (unsigned short*)(base + take((size_t)NJ * H * H * 2));
    unsigned short* WTa2 = (unsigned short*)(base + take((size_t)NJ * H * H * 2));
    float* biasP   = (float*)(base + take(2 * H * 4));
    unsigned short* xb  = (unsigned short*)(base + take((size_t)N * H * 2));
    unsigned short* hb  = (unsigned short*)(base + take((size_t)N * H * 2));
    (void)ws_size;

    const int nbScan = (N + 255) / 256;

    zero_kernel<<<512, 256, 0, stream>>>(cnt, (long)N * (2 * RREL));  // cnt + cursor8
    count_kernel<<<(E + 255) / 256, 256, 0, stream>>>(edge_index, edge_type, cnt, E);
    scan_block_kernel<<<nbScan, 256, 0, stream>>>(cnt, rploc, bsum, N);
    finalize_kernel<<<nbScan, 256, 0, stream>>>(cnt, rploc, bsum, rowptr, rowptr2, inv, N, nbScan);
    fill_kernel<<<(E + 255) / 256, 256, 0, stream>>>(edge_index, edge_type, cursor8, rowptr2, packed, E);
    wcat_tobf_kernel<<<2048, 256, 0, stream>>>(W1, root1, W2, root2, b1, b2,
                                               WTa1, WTa2, biasP, node_emb, xb, (long)N * H);

    const int gl = (N + MT - 1) / MT;
    layer_kernel<<<gl, 512, 0, stream>>>(xb, WTa1, biasP, inv, rowptr, packed,
                                         nullptr, hb, N, 1);
    layer_kernel<<<gl, 512, 0, stream>>>(hb, WTa2, biasP + H, inv, rowptr, packed,
                                         out, nullptr, N, 0);
}